// Round 1
// baseline (494.376 us; speedup 1.0000x reference)
//
#include <hip/hip_runtime.h>
#include <stdint.h>

// Problem constants
#define Bz 32
#define Tz 64
#define Nz 1000
#define Cz 8
#define HGz 16
#define HLz 256
#define OUTz 24
#define Ez 16000
#define K2z 8000   // N*C (folded GEMM K)
#define Mz 2048    // B*T
#define G4z 1024   // 4*HL
#define NSz 8      // split-K count

using half8  = __attribute__((ext_vector_type(8))) _Float16;
using half4  = __attribute__((ext_vector_type(4))) _Float16;
using floatx4 = __attribute__((ext_vector_type(4))) float;

#define SENT 0x7E7E7E7E7E7E7E7EULL  // 4x fp16 NaN, memset-able byte 0x7E

// ---- Workspace layout (bytes) ----
static const size_t OFF_IDEG   = 4096;      // fp32 [1000]
static const size_t OFF_CNT    = 73728;     // int  [1024]
static const size_t OFF_ROFF   = 77824;     // int  [1024]
static const size_t OFF_CSRS   = 86016;     // int  [16000]
static const size_t OFF_CSRW   = 151552;    // fp32 [16000]
static const size_t OFF_HLAST  = 217088;    // fp32 [32][256]
static const size_t OFF_PRE16T = 249856;    // fp16 [64][1024][32]  4,194,304
static const size_t OFF_WHH16  = 4444160;   // fp16 [1024][256]       524,288
static const size_t OFF_HX     = 4968448;   // u64  [2][64][2][128][4] 1,048,576
static const size_t OFF_BGC    = 6037504;   // fp32 [1024]
static const size_t OFF_XT     = 6041600;   // fp16 [2048][8000]   32,768,000
static const size_t OFF_WC     = 38809600;  // fp16 [1024][8000]   16,384,000
static const size_t OFF_PRES   = 55193600;  // fp16 [8][2048][1024] 33,554,432
static const size_t WS_NEED    = 88748032;

__device__ __forceinline__ void gl_lds16(const void* g, void* l) {
  __builtin_amdgcn_global_load_lds(
      (__attribute__((address_space(1))) void*)(void*)g,
      (__attribute__((address_space(3))) void*)l, 16, 0, 0);
}

__device__ __forceinline__ float sigm(float x) { return 1.0f / (1.0f + __expf(-x)); }
__device__ __forceinline__ float tanhh(float x) { return 1.0f - 2.0f / (__expf(2.0f * x) + 1.0f); }

// ---------------- fused GCN prep: deg, norm, CSR (one WG, LDS atomics + LDS scan) ----------------
__global__ void __launch_bounds__(1024) k_prep(const int* __restrict__ ei,
                                               const float* __restrict__ ew,
                                               float* __restrict__ ideg,
                                               int* __restrict__ cntg,
                                               int* __restrict__ roffg,
                                               int* __restrict__ csrs,
                                               float* __restrict__ csrw) {
  __shared__ float disS[1024];   // deg, then 1/sqrt(deg)
  __shared__ int   cntS[1024];
  __shared__ int   curS[1024];
  __shared__ int   scanS[1024];
  int tid = threadIdx.x;
  disS[tid] = 1.0f;
  cntS[tid] = 0;
  __syncthreads();
  for (int e = tid; e < Ez; e += 1024) {
    int col = ei[Ez + e];
    atomicAdd(&disS[col], ew[e]);
    atomicAdd(&cntS[col], 1);
  }
  __syncthreads();
  float d = disS[tid];
  float dis = 1.0f / sqrtf(d);
  if (tid < Nz) ideg[tid] = 1.0f / d;
  __syncthreads();
  disS[tid] = dis;
  // exclusive scan of cnt
  int v0 = cntS[tid];
  scanS[tid] = v0;
  __syncthreads();
  for (int off = 1; off < 1024; off <<= 1) {
    int v = (tid >= off) ? scanS[tid - off] : 0;
    __syncthreads();
    scanS[tid] += v;
    __syncthreads();
  }
  int excl = scanS[tid] - v0;
  roffg[tid] = excl;
  cntg[tid] = v0;
  curS[tid] = excl;
  __syncthreads();
  for (int e = tid; e < Ez; e += 1024) {
    int row = ei[e], col = ei[Ez + e];
    int p = atomicAdd(&curS[col], 1);
    csrs[p] = row;
    csrw[p] = disS[row] * ew[e] * disS[col];
  }
}

// Fold W_gcn into W_ih (blocks 0..1023); blocks 1024..1151 cast Whh -> fp16.
__global__ void __launch_bounds__(256) k_fold(const float* __restrict__ Wih,
                                              const float* __restrict__ Wg,
                                              const float* __restrict__ bg,
                                              _Float16* __restrict__ wc,
                                              float* __restrict__ bgc,
                                              const float* __restrict__ Whh,
                                              _Float16* __restrict__ whh16) {
  __shared__ float wgs[Cz * HGz];
  __shared__ float bgs[HGz];
  __shared__ float red[256];
  int tid = threadIdx.x;
  int j = blockIdx.x;
  if (j >= 1024) {
    size_t i = (size_t)(j - 1024) * 256 + tid;  // 32768 half8s
    float4 a = ((const float4*)Whh)[i * 2];
    float4 b = ((const float4*)Whh)[i * 2 + 1];
    half8 h;
    h[0] = (_Float16)a.x; h[1] = (_Float16)a.y; h[2] = (_Float16)a.z; h[3] = (_Float16)a.w;
    h[4] = (_Float16)b.x; h[5] = (_Float16)b.y; h[6] = (_Float16)b.z; h[7] = (_Float16)b.w;
    ((half8*)whh16)[i] = h;
    return;
  }
  if (tid < Cz * HGz) wgs[tid] = Wg[tid];
  if (tid < HGz) bgs[tid] = bg[tid];
  __syncthreads();
  const float* row = Wih + (size_t)j * (Nz * HGz);
  float bacc = 0.f;
  for (int n = tid; n < Nz; n += 256) {
    const float* p = row + n * HGz;
    float w[16];
    float4 v0 = *(const float4*)p, v1 = *(const float4*)(p + 4);
    float4 v2 = *(const float4*)(p + 8), v3 = *(const float4*)(p + 12);
    w[0]=v0.x; w[1]=v0.y; w[2]=v0.z; w[3]=v0.w;
    w[4]=v1.x; w[5]=v1.y; w[6]=v1.z; w[7]=v1.w;
    w[8]=v2.x; w[9]=v2.y; w[10]=v2.z; w[11]=v2.w;
    w[12]=v3.x; w[13]=v3.y; w[14]=v3.z; w[15]=v3.w;
    half8 o;
#pragma unroll
    for (int c = 0; c < Cz; ++c) {
      float s = 0.f;
#pragma unroll
      for (int h = 0; h < HGz; ++h) s += w[h] * wgs[c * HGz + h];
      o[c] = (_Float16)s;
    }
#pragma unroll
    for (int h = 0; h < HGz; ++h) bacc += w[h] * bgs[h];
    *(half8*)(wc + (size_t)j * K2z + n * Cz) = o;
  }
  red[tid] = bacc;
  __syncthreads();
  for (int off = 128; off > 0; off >>= 1) {
    if (tid < off) red[tid] += red[tid + off];
    __syncthreads();
  }
  if (tid == 0) bgc[j] = red[0];
}

// xt: blocks 0..249 = batch-0 rows (ideg*x + CSR neighbor agg); blocks 250..7999 = fp16 cast of x batches 1..31.
__global__ void k_xt(const float* __restrict__ x, const float* __restrict__ ideg,
                     const int* __restrict__ roff, const int* __restrict__ cnt,
                     const int* __restrict__ csrs, const float* __restrict__ csrw,
                     _Float16* __restrict__ xt) {
  if (blockIdx.x >= 250) {
    size_t i = (size_t)(blockIdx.x - 250) * 256 + threadIdx.x;
    const float* src = x + (size_t)Tz * K2z;
    _Float16* dst = xt + (size_t)Tz * K2z;
    float4 a = ((const float4*)src)[i * 2];
    float4 b = ((const float4*)src)[i * 2 + 1];
    half8 h;
    h[0] = (_Float16)a.x; h[1] = (_Float16)a.y; h[2] = (_Float16)a.z; h[3] = (_Float16)a.w;
    h[4] = (_Float16)b.x; h[5] = (_Float16)b.y; h[6] = (_Float16)b.z; h[7] = (_Float16)b.w;
    ((half8*)dst)[i] = h;
    return;
  }
  int g = blockIdx.x * 256 + threadIdx.x;  // t*1000+n
  if (g >= Tz * Nz) return;
  int t = g / Nz, n = g % Nz;
  const float* xp = x + (size_t)g * Cz;
  float4 a = *(const float4*)xp, b = *(const float4*)(xp + 4);
  float id = ideg[n];
  float s[8] = {id*a.x, id*a.y, id*a.z, id*a.w, id*b.x, id*b.y, id*b.z, id*b.w};
  int i0 = roff[n], nc = cnt[n];
  for (int i = i0; i < i0 + nc; ++i) {
    int src = csrs[i];
    float wv = csrw[i];
    const float* q = x + ((size_t)t * Nz + src) * Cz;
    float4 u = *(const float4*)q, v = *(const float4*)(q + 4);
    s[0] += wv * u.x; s[1] += wv * u.y; s[2] += wv * u.z; s[3] += wv * u.w;
    s[4] += wv * v.x; s[5] += wv * v.y; s[6] += wv * v.z; s[7] += wv * v.w;
  }
  half8 h;
#pragma unroll
  for (int c = 0; c < 8; ++c) h[c] = (_Float16)s[c];
  *(half8*)(xt + (size_t)t * K2z + n * Cz) = h;
}

// ---------------- GEMM: preS[z][2048][1024] (fp16) = xt @ Wc^T, uneven split-K=8 ----------------
// z<7: K window 1024 (32 iters); z=7: 832 (26 iters). 1024 WGs -> 3-4 blocks/CU co-resident.
__global__ void __launch_bounds__(256) k_gemm(const _Float16* __restrict__ A,
                                              const _Float16* __restrict__ Bm,
                                              _Float16* __restrict__ Cp) {
  __shared__ _Float16 As[128 * 32];
  __shared__ _Float16 Bs[128 * 32];
  const int tid = threadIdx.x;
  const int lane = tid & 63;
  const int wave = tid >> 6;
  const int wm = wave & 1, wn = wave >> 1;
  const int quad = lane >> 4, l15 = lane & 15;
  const size_t tm = (size_t)blockIdx.x * 128;
  const size_t tn = (size_t)blockIdx.y * 128;
  const int k0 = blockIdx.z * 1024;
  const int iters = (blockIdx.z < 7) ? 32 : 26;   // 7*1024 + 832 = 8000
  _Float16* Cz_ = Cp + (size_t)blockIdx.z * Mz * G4z;
  const int srow = tid >> 2;
  const int skk = (tid & 3) * 8;
  const _Float16* gA0 = A + (tm + srow) * (size_t)K2z + k0 + skk;
  const _Float16* gA1 = gA0 + 64 * (size_t)K2z;
  const _Float16* gB0 = Bm + (tn + srow) * (size_t)K2z + k0 + skk;
  const _Float16* gB1 = gB0 + 64 * (size_t)K2z;
  _Float16* lA0 = &As[tid * 8];
  _Float16* lA1 = &As[2048 + tid * 8];
  _Float16* lB0 = &Bs[tid * 8];
  _Float16* lB1 = &Bs[2048 + tid * 8];
  floatx4 acc[4][4] = {};
  for (int kt = 0; kt < iters; ++kt) {
    __syncthreads();
    gl_lds16(gA0, lA0);
    gl_lds16(gA1, lA1);
    gl_lds16(gB0, lB0);
    gl_lds16(gB1, lB1);
    gA0 += 32; gA1 += 32; gB0 += 32; gB1 += 32;
    __syncthreads();
    half8 af[4], bf[4];
#pragma unroll
    for (int i = 0; i < 4; ++i)
      af[i] = *(const half8*)&As[(wm * 64 + i * 16 + l15) * 32 + quad * 8];
#pragma unroll
    for (int i = 0; i < 4; ++i)
      bf[i] = *(const half8*)&Bs[(wn * 64 + i * 16 + l15) * 32 + quad * 8];
#pragma unroll
    for (int mi = 0; mi < 4; ++mi)
#pragma unroll
      for (int ni = 0; ni < 4; ++ni)
        acc[mi][ni] = __builtin_amdgcn_mfma_f32_16x16x32_f16(af[mi], bf[ni], acc[mi][ni], 0, 0, 0);
  }
#pragma unroll
  for (int mi = 0; mi < 4; ++mi)
#pragma unroll
    for (int ni = 0; ni < 4; ++ni) {
      size_t r0 = tm + wm * 64 + mi * 16 + quad * 4;
      size_t cc = tn + wn * 64 + ni * 16 + l15;
#pragma unroll
      for (int q = 0; q < 4; ++q) Cz_[(r0 + q) * G4z + cc] = (_Float16)acc[mi][ni][q];
    }
}

// ---------------- reduce fp16 split-K + biases -> transposed fp16 pre[t][j][batch] ----------------
__global__ void k_reduce(const _Float16* __restrict__ preS, const float* __restrict__ bih,
                         const float* __restrict__ bhh, const float* __restrict__ bgc,
                         _Float16* __restrict__ preT) {
  int t = blockIdx.x;                      // 0..63
  int j = blockIdx.y * 256 + threadIdx.x;  // 0..1023
  float bias = bih[j] + bhh[j] + bgc[j];
  float v[32];
#pragma unroll
  for (int b = 0; b < 32; ++b) v[b] = bias;
  for (int s = 0; s < NSz; ++s) {
    const _Float16* base = preS + (size_t)s * Mz * G4z;
#pragma unroll
    for (int b = 0; b < 32; ++b)
      v[b] += (float)base[((size_t)b * Tz + t) * G4z + j];
  }
  half8 h[4];
#pragma unroll
  for (int i = 0; i < 32; ++i) ((_Float16*)h)[i] = (_Float16)v[i];
  half8* op = (half8*)(preT + ((size_t)t * G4z + j) * Bz);
#pragma unroll
  for (int i = 0; i < 4; ++i) op[i] = h[i];
}

// ---------------- LSTM v2: 4 real blocks = (2 batch-groups of 16) x (2 hl-halves of W) ------------
// M=16 full m-tile (no pad waste). Block owns all 4 gates for its 128-hl half -> pointwise local.
// W half: gates i,f in LDS (128 KB), gates g,o in 64 VGPR/lane. Single-peer exchange via
// NaN-sentinel u64 data-polling; own-half-K MFMA is issued BEFORE the poll so the peer store's
// flight time hides under the matrix pipe. 2 barriers/step, parity-double-buffered h in LDS.
template <int KB>
__device__ __forceinline__ void mfma_phase(const _Float16* hrow,
                                           const _Float16* wb0,
                                           const _Float16* wb1,
                                           const half8 (&wreg)[2][8],
                                           floatx4 (&acc)[4]) {
#pragma unroll
  for (int kk = 0; kk < 4; ++kk) {
    const int kt = KB + kk;                       // compile-time after unroll (rule #20 safe)
    half8 a  = *(const half8*)(hrow + kt * 32);
    half8 b0 = *(const half8*)(wb0 + kt * 32);
    half8 b1 = *(const half8*)(wb1 + kt * 32);
    acc[0] = __builtin_amdgcn_mfma_f32_16x16x32_f16(a, b0, acc[0], 0, 0, 0);
    acc[1] = __builtin_amdgcn_mfma_f32_16x16x32_f16(a, b1, acc[1], 0, 0, 0);
    acc[2] = __builtin_amdgcn_mfma_f32_16x16x32_f16(a, wreg[0][kt], acc[2], 0, 0, 0);
    acc[3] = __builtin_amdgcn_mfma_f32_16x16x32_f16(a, wreg[1][kt], acc[3], 0, 0, 0);
  }
}

__global__ void __launch_bounds__(512) k_lstm2(const _Float16* __restrict__ Whh16,
                                               const _Float16* __restrict__ preT,
                                               unsigned long long* __restrict__ hx, // [2][64][2][128][4]
                                               float* __restrict__ hlast) {         // [32][256]
  // grid=16 with 12 dummies: real blocks at idx {0,1,8,9} so each communicating pair
  // (bg,0)-(bg,1) shares the same blockIdx%8 slot (same-XCD if dispatch is round-robin).
  const int sub = blockIdx.x & 7;
  if (sub > 1) return;
  const int bg = sub;                  // batch group: batches bg*16 .. bg*16+15
  const int hh = blockIdx.x >> 3;      // hl half: hl in [hh*128, hh*128+128)

  __shared__ _Float16 Ws[8 * 2 * 16 * 264];   // [wave][gate i/f][row16][264]  135168 B
  __shared__ _Float16 hb[2 * 16 * 264];       // [parity][batch16][264]         16896 B

  const int tid = threadIdx.x;
  const int w = tid >> 6;
  const int lane = tid & 63;
  const int quad = lane >> 4, l15 = lane & 15;

  // zero h (h0 = 0, both parities; cols never written stay 0 only until staged)
  for (int i = tid; i < 2 * 16 * 264; i += 512) hb[i] = (_Float16)0.f;

  // LDS W: gates 0(i),1(f) for this hl-half. 256 rows x 32 half8.
  for (int i = tid; i < 256 * 32; i += 512) {
    int lr = i >> 5, u = i & 31;
    int g = lr >> 7, rr = lr & 127;
    int ww = rr >> 4, r = rr & 15;
    int grow = g * 256 + hh * 128 + rr;
    *(half8*)&Ws[(((ww * 2 + g) * 16 + r) * 264) + u * 8] =
        *(const half8*)(Whh16 + (size_t)grow * 256 + u * 8);
  }
  // reg W: gates 2(g),3(o): 16 half8 = 64 VGPR/lane, full K resident.
  half8 wreg[2][8];
#pragma unroll
  for (int g = 0; g < 2; ++g) {
    const _Float16* src = Whh16 + ((size_t)(g + 2) * 256 + hh * 128 + w * 16 + l15) * 256 + quad * 8;
#pragma unroll
    for (int kt = 0; kt < 8; ++kt) wreg[g][kt] = *(const half8*)(src + kt * 32);
  }

  const int hlL = w * 16 + l15;          // local hl within half: 0..127
  const int hlG = hh * 128 + hlL;        // global hl: 0..255
  // exchange word linear layout: (((bg*64 + t)*2 + half)*128 + hl)*4 + bh ; tid == hl*4+bh
  unsigned long long* pubBase = hx + ((size_t)bg * 64 * 2 + hh) * 512 + (size_t)hlL * 4 + quad;
  const unsigned long long* polBase = hx + ((size_t)bg * 64 * 2 + (hh ^ 1)) * 512 + tid;

  const _Float16* wb0 = &Ws[((w * 2 + 0) * 16 + l15) * 264 + quad * 8];
  const _Float16* wb1 = &Ws[((w * 2 + 1) * 16 + l15) * 264 + quad * 8];

  float cst[4] = {0.f, 0.f, 0.f, 0.f};
  __syncthreads();

  for (int t = 0; t < Tz; ++t) {
    const int p = t & 1;
    // pq loads (independent of h): issue early, consumed at pointwise. All 64 lanes, 8 B each.
    half4 pq[4];
    const _Float16* pT = preT + (size_t)t * (G4z * Bz) + bg * 16 + quad * 4;
#pragma unroll
    for (int g = 0; g < 4; ++g)
      pq[g] = *(const half4*)(pT + (size_t)(g * 256 + hlG) * Bz);

    floatx4 acc[4] = {};
    const _Float16* hrow = &hb[p * (16 * 264) + l15 * 264 + quad * 8];

    // own-half K first: data already in LDS, MFMAs issue-and-forget -> poll overlaps the pipe.
    if (hh == 0) mfma_phase<0>(hrow, wb0, wb1, wreg, acc);
    else         mfma_phase<4>(hrow, wb0, wb1, wreg, acc);

    // poll the single peer's 512 words (one per thread), stage into this parity's peer columns
    if (t > 0) {
      const unsigned long long* src = polBase + (size_t)t * 1024;
      unsigned long long u;
      while ((u = __hip_atomic_load(src, __ATOMIC_RELAXED, __HIP_MEMORY_SCOPE_AGENT)) == SENT)
        __builtin_amdgcn_s_sleep(1);
      half4 hv = __builtin_bit_cast(half4, u);
      const int phl = tid >> 2, pbh = tid & 3;
      _Float16* dst = &hb[p * (16 * 264) + (pbh * 4) * 264 + ((hh ^ 1) * 128 + phl)];
#pragma unroll
      for (int q = 0; q < 4; ++q) dst[q * 264] = hv[q];
    }
    __syncthreads();

    // remote-half K
    if (hh == 0) mfma_phase<4>(hrow, wb0, wb1, wreg, acc);
    else         mfma_phase<0>(hrow, wb0, wb1, wreg, acc);

    // pointwise: all 64 lanes real (batch = quad*4+q, hl = hlG)
    half4 o4;
#pragma unroll
    for (int q = 0; q < 4; ++q) {
      float gi = acc[0][q] + (float)pq[0][q];
      float gf = acc[1][q] + (float)pq[1][q];
      float gg = acc[2][q] + (float)pq[2][q];
      float go = acc[3][q] + (float)pq[3][q];
      float iv = sigm(gi), fv = sigm(gf), gv = tanhh(gg), ov = sigm(go);
      float cn = fv * cst[q] + iv * gv;
      cst[q] = cn;
      float hn = ov * tanhh(cn);
      o4[q] = (_Float16)hn;
      if (t == Tz - 1) hlast[(size_t)(bg * 16 + quad * 4 + q) * HLz + hlG] = hn;
    }
    if (t < Tz - 1) {
      // publish first (global latency), then own-half into next parity's LDS
      __hip_atomic_store(pubBase + (size_t)(t + 1) * 1024,
                         __builtin_bit_cast(unsigned long long, o4),
                         __ATOMIC_RELAXED, __HIP_MEMORY_SCOPE_AGENT);
      _Float16* dst = &hb[(p ^ 1) * (16 * 264) + (quad * 4) * 264 + hlG];
#pragma unroll
      for (int q = 0; q < 4; ++q) dst[q * 264] = o4[q];
    }
    __syncthreads();
  }
}

// out[b,o] = h_last[b,:] @ W_proj[o,:] + b_proj[o]
__global__ void k_proj(const float* __restrict__ hlast, const float* __restrict__ Wp,
                       const float* __restrict__ bp, float* __restrict__ out) {
  int idx = blockIdx.x * 256 + threadIdx.x;
  if (idx >= Bz * OUTz) return;
  int b = idx / OUTz, o = idx % OUTz;
  const float* h = hlast + (size_t)b * HLz;
  const float* wr = Wp + (size_t)o * HLz;
  float s = 0.f;
  for (int k = 0; k < HLz; k += 4) {
    float4 hv = *(const float4*)&h[k];
    float4 wv = *(const float4*)&wr[k];
    s += hv.x * wv.x + hv.y * wv.y + hv.z * wv.z + hv.w * wv.w;
  }
  out[idx] = s + bp[o];
}

extern "C" void kernel_launch(void* const* d_in, const int* in_sizes, int n_in,
                              void* d_out, int out_size, void* d_ws, size_t ws_size,
                              hipStream_t stream) {
  const float* x   = (const float*)d_in[0];
  const int*   ei  = (const int*)d_in[1];
  const float* ew  = (const float*)d_in[2];
  const float* Wg  = (const float*)d_in[3];
  const float* bg  = (const float*)d_in[4];
  const float* Wih = (const float*)d_in[5];
  const float* Whh = (const float*)d_in[6];
  const float* bih = (const float*)d_in[7];
  const float* bhh = (const float*)d_in[8];
  const float* Wp  = (const float*)d_in[9];
  const float* bp  = (const float*)d_in[10];
  float* out = (float*)d_out;
  char* ws = (char*)d_ws;
  if (ws_size < WS_NEED) return;

  float* ideg  = (float*)(ws + OFF_IDEG);
  int*   cnt   = (int*)(ws + OFF_CNT);
  int*   roff  = (int*)(ws + OFF_ROFF);
  int*   csrs  = (int*)(ws + OFF_CSRS);
  float* csrw  = (float*)(ws + OFF_CSRW);
  float* hlast = (float*)(ws + OFF_HLAST);
  _Float16* preT  = (_Float16*)(ws + OFF_PRE16T);
  _Float16* whh16 = (_Float16*)(ws + OFF_WHH16);
  unsigned long long* hx = (unsigned long long*)(ws + OFF_HX);
  float* bgc   = (float*)(ws + OFF_BGC);
  _Float16* xt    = (_Float16*)(ws + OFF_XT);
  _Float16* wc    = (_Float16*)(ws + OFF_WC);
  _Float16* preS  = (_Float16*)(ws + OFF_PRES);

  // hx = NaN sentinel (byte-uniform); slot t=0 is never read (h0=0 handled in-kernel)
  hipMemsetAsync(ws + OFF_HX, 0x7E, (size_t)2 * 64 * 2 * 128 * 4 * 8, stream);

  k_prep<<<1, 1024, 0, stream>>>(ei, ew, ideg, cnt, roff, csrs, csrw);
  k_fold<<<1152, 256, 0, stream>>>(Wih, Wg, bg, wc, bgc, Whh, whh16);
  k_xt<<<8000, 256, 0, stream>>>(x, ideg, roff, cnt, csrs, csrw, xt);
  k_gemm<<<dim3(16, 8, NSz), 256, 0, stream>>>(xt, wc, preS);
  k_reduce<<<dim3(Tz, 4), 256, 0, stream>>>(preS, bih, bhh, bgc, preT);
  k_lstm2<<<16, 512, 0, stream>>>(whh16, preT, hx, hlast);
  k_proj<<<3, 256, 0, stream>>>(hlast, Wp, bp, out);
}